// Round 4
// baseline (541.069 us; speedup 1.0000x reference)
//
#include <hip/hip_runtime.h>
#include <cstdint>
#include <cmath>

#define NN 8000
#define NE 64000
#define DNE 128
#define NHD 8
#define CDIM 640

typedef unsigned short u16;
typedef u16   u16x8 __attribute__((ext_vector_type(8)));
typedef __bf16 v8bf __attribute__((ext_vector_type(8)));
typedef float  v4f  __attribute__((ext_vector_type(4)));

static __device__ __forceinline__ u16 f2bf(float f) {
    unsigned int u = __float_as_uint(f);
    u += 0x7FFF + ((u >> 16) & 1);
    return (u16)(u >> 16);
}
static __device__ __forceinline__ float bf2f(u16 v) {
    return __uint_as_float(((unsigned int)v) << 16);
}
static __device__ __forceinline__ float silu(float v) {
    return v / (1.0f + __expf(-v));
}

// ---------------- workspace byte offsets ----------------
constexpr size_t O_TBF   = 0;                          // 64000x128 bf16
constexpr size_t O_X1BF  = 16384000;                   // 24064x128
constexpr size_t O_X2BF  = O_X1BF  + 6160384;          // 40064x128
constexpr size_t O_WARE  = O_X2BF  + 10256384;         // 405504 u16
constexpr size_t O_CNT   = O_WARE  + 811008;
constexpr size_t O_CURS  = O_CNT   + 32000;
constexpr size_t O_OFFS  = O_CURS  + 32000;
constexpr size_t O_EIDS  = O_OFFS  + 32768;
constexpr size_t O_HV    = O_EIDS  + 256000;           // 8064x640 bf16
constexpr size_t O_HS    = O_HV    + 10321920;
constexpr size_t O_ATTN  = O_HS    + 10321920;         // 64000x8 f32
constexpr size_t O_B512  = O_ATTN  + 2048000;          // 512 f32
constexpr size_t O_TEMP  = O_B512  + 2048;
// early phase:
constexpr size_t O_QKVS  = O_TEMP;                     // 8064x512 bf16
constexpr size_t O_ALPHA = O_QKVS + 8257536;           // 64000x8 f32
constexpr size_t O_HBF   = O_ALPHA + 2048000;          // 8064x128 bf16
// coeff phase:
constexpr size_t O_COEFF = O_TEMP;                     // 64000x640 bf16
// post-scatter phase:
constexpr size_t O_Q1K1  = O_TEMP;                     // 24064x128 bf16
constexpr size_t O_Q2K2  = O_Q1K1 + 6160384;           // 40064x128 bf16
constexpr size_t O_WBUF  = O_Q2K2 + 10256384;          // 64000x64 bf16
constexpr size_t O_WOUT  = O_WBUF + 8192000;           // 64000x128 bf16

// weight arena u16 offsets
// 0:Wq 1:Wk 2:Wv1 3:Ws1 4:Wre 5:Wt1 6:Wt2 7:Wv2 8:Wrs 9:Ws2 10:Ww1 11:Ww2 12:WA1 13:WA2
__device__ const int WOFFA[14] = {0,16384,32768,49152,65536,81920,98304,114688,196608,278528,360448,364544,372736,389120};

// ---------------- fused weight convert/transpose + bias pack + zeroing ----------------
struct WTArgs { const float* w[16]; const float* b[4]; };
__global__ void wtrans_all(WTArgs a, u16* __restrict__ ob, float* __restrict__ bias512,
                           int* __restrict__ zeroa) {
    int s = blockIdx.y;
    int id = blockIdx.x * 256 + threadIdx.x;
    if (s < 12) {
        int K = (s < 10) ? 128 : 64;
        int N = (s < 7) ? 128 : ((s < 10) ? 640 : ((s == 10) ? 64 : 128));
        if (id >= K * N) return;
        int k = id / N, n = id % N;
        ob[WOFFA[s] + (size_t)n * K + k] = f2bf(a.w[s][id]);
    } else if (s < 14) {
        if (id >= 16384) return;
        int n = id >> 7, k = id & 127;
        const float* wa = a.w[s == 12 ? 12 : 14];
        const float* wb = a.w[s == 12 ? 13 : 15];
        ob[WOFFA[s] + id] = f2bf(n < 64 ? wa[k * 64 + n] : wb[k * 64 + (n - 64)]);
    } else if (s == 14) {
        if (id >= 512) return;
        bias512[id] = a.b[id >> 7][id & 127];
    } else {
        if (id < 16000) zeroa[id] = 0;
    }
}

// ---------------- activation fp32->bf16 convert ----------------
struct ConvArgs { const float* in[4]; u16* out[4]; };
__global__ void conv_all(ConvArgs a) {
    int s = blockIdx.y;
    int padr = (s == 0) ? 8064 : ((s == 1) ? 64000 : ((s == 2) ? 24064 : 40064));
    int realr = (s == 0) ? 8000 : ((s == 1) ? 64000 : ((s == 2) ? 24000 : 40000));
    int id4 = (blockIdx.x * 256 + threadIdx.x) * 4;
    if (id4 >= padr * 128) return;
    int row = id4 >> 7;
    float4 v = make_float4(0.f, 0.f, 0.f, 0.f);
    if (row < realr) v = *(const float4*)(a.in[s] + id4);
    u16* o = a.out[s] + id4;
    o[0] = f2bf(v.x); o[1] = f2bf(v.y); o[2] = f2bf(v.z); o[3] = f2bf(v.w);
}

// ---------------- unified MFMA GEMM body (dynamic LDS) ----------------
// MODE 0: bf16 out = acc+bias?, act 1=silu, 2=silu if gcol>=256
// MODE 2: coeff epilogue   MODE 4: alpha epilogue
// AF32: A read from fp32 with row clamp at Areal (pads -> 0)
template<int MODE, bool AF32>
__device__ __forceinline__ void mm_body(
    char* smem,
    const u16* __restrict__ A, const float* __restrict__ Af, int As, int Areal,
    const u16* __restrict__ Bt, const float* __restrict__ bias,
    void* __restrict__ out, int Ncols, int K, int act,
    const int* __restrict__ edge, const float* __restrict__ attn,
    const u16* __restrict__ hv, const u16* __restrict__ hs,
    const float* __restrict__ cvals, int bx, int by)
{
    constexpr int LDA = 40;
    u16* sA = (u16*)smem;                   // 128*40*2 = 10240
    u16* sB = (u16*)(smem + 10240);         // 10240
    float* attnL = (float*)(smem + 20480);  // MODE2: 4096
    float* ceL   = (float*)(smem + 24576);  // MODE2: 512
    int*   jnL   = (int*)(smem + 25088);    // MODE2: 512
    int*   iL    = (int*)(smem + 20480);    // MODE4: 512
    int*   jL    = (int*)(smem + 20992);    // MODE4: 512
    const int tid = threadIdx.x;
    const int wave = tid >> 6, lane = tid & 63;
    const int lane15 = lane & 15, quad = lane >> 4;
    const int wm = wave >> 1, wn = wave & 1;
    const int row0 = by * 128, col0 = bx * 128;
    const int arow = wm * 64, brow = wn * 64;

    if (MODE == 2) {
        for (int q = tid; q < 1024; q += 256)
            attnL[q] = attn[(size_t)(row0 + (q >> 3)) * NHD + (q & 7)];
        if (tid < 128) { ceL[tid] = cvals[row0 + tid]; jnL[tid] = edge[2 * (row0 + tid) + 1]; }
    }
    if (MODE == 4) {
        if (tid < 128) { int e = row0 + tid; iL[tid] = edge[2 * e]; jL[tid] = edge[2 * e + 1]; }
    }

    v4f acc[4][4] = {};
    for (int k0 = 0; k0 < K; k0 += 32) {
        #pragma unroll
        for (int ci = 0; ci < 2; ++ci) {
            int cch = tid + ci * 256;
            int m = cch >> 2, ko = (cch & 3) * 8;
            int row = row0 + m;
            if (AF32) {
                u16 tmp[8];
                if (row < Areal) {
                    const float* src = Af + (size_t)row * As + k0 + ko;
                    #pragma unroll
                    for (int q = 0; q < 8; ++q) tmp[q] = f2bf(src[q]);
                } else {
                    #pragma unroll
                    for (int q = 0; q < 8; ++q) tmp[q] = 0;
                }
                *(u16x8*)(&sA[m * LDA + ko]) = *(u16x8*)tmp;
            } else {
                *(u16x8*)(&sA[m * LDA + ko]) = *(const u16x8*)(A + (size_t)row * As + k0 + ko);
            }
        }
        #pragma unroll
        for (int ci = 0; ci < 2; ++ci) {
            int cch = tid + ci * 256;
            int n = cch >> 2, ko = (cch & 3) * 8;
            *(u16x8*)(&sB[n * LDA + ko]) = *(const u16x8*)(Bt + (size_t)(col0 + n) * K + k0 + ko);
        }
        __syncthreads();
        v8bf af[4], bfr[4];
        #pragma unroll
        for (int mt = 0; mt < 4; ++mt)
            af[mt] = __builtin_bit_cast(v8bf, *(const u16x8*)(&sA[(arow + mt * 16 + lane15) * LDA + quad * 8]));
        #pragma unroll
        for (int nt = 0; nt < 4; ++nt)
            bfr[nt] = __builtin_bit_cast(v8bf, *(const u16x8*)(&sB[(brow + nt * 16 + lane15) * LDA + quad * 8]));
        #pragma unroll
        for (int mt = 0; mt < 4; ++mt)
            #pragma unroll
            for (int nt = 0; nt < 4; ++nt)
                acc[mt][nt] = __builtin_amdgcn_mfma_f32_16x16x32_bf16(af[mt], bfr[nt], acc[mt][nt], 0, 0, 0);
        __syncthreads();
    }

    if (MODE == 2) {
        #pragma unroll
        for (int mt = 0; mt < 4; ++mt) {
            int lrow[4];
            const u16 *hvp[4], *hsp[4];
            #pragma unroll
            for (int r = 0; r < 4; ++r) {
                int lr = arow + mt * 16 + quad * 4 + r;
                lrow[r] = lr;
                int jn = jnL[lr];
                hvp[r] = hv + (size_t)jn * CDIM;
                hsp[r] = hs + (size_t)jn * CDIM;
            }
            u16 hvv[4][4], hsv[4][4];
            #pragma unroll
            for (int r = 0; r < 4; ++r)
                #pragma unroll
                for (int nt = 0; nt < 4; ++nt) {
                    int gcol = col0 + brow + nt * 16 + lane15;
                    hvv[r][nt] = hvp[r][gcol];
                    hsv[r][nt] = hsp[r][gcol];
                }
            #pragma unroll
            for (int r = 0; r < 4; ++r) {
                int lr = lrow[r];
                float ce = ceL[lr];
                u16* orow = (u16*)out + (size_t)(row0 + lr) * CDIM;
                #pragma unroll
                for (int nt = 0; nt < 4; ++nt) {
                    int gcol = col0 + brow + nt * 16 + lane15;
                    float tp = acc[mt][nt][r] + bias[gcol];
                    float at = attnL[lr * 8 + gcol / 80];
                    orow[gcol] = f2bf(at * bf2f(hvv[r][nt]) + tp * bf2f(hsv[r][nt]) * ce);
                }
            }
        }
    } else if (MODE == 4) {
        #pragma unroll
        for (int mt = 0; mt < 4; ++mt) {
            int lrow[4];
            const u16 *qp[4], *kp[4];
            #pragma unroll
            for (int r = 0; r < 4; ++r) {
                int lr = arow + mt * 16 + quad * 4 + r;
                lrow[r] = lr;
                qp[r] = hv + (size_t)iL[lr] * 512;        // hq slice of qkvs
                kp[r] = hv + (size_t)jL[lr] * 512 + 128;  // hk slice
            }
            u16 qv[4][4], kv[4][4];
            #pragma unroll
            for (int r = 0; r < 4; ++r)
                #pragma unroll
                for (int nt = 0; nt < 4; ++nt) {
                    int gcol = brow + nt * 16 + lane15;
                    qv[r][nt] = qp[r][gcol];
                    kv[r][nt] = kp[r][gcol];
                }
            #pragma unroll
            for (int r = 0; r < 4; ++r) {
                int lr = lrow[r];
                #pragma unroll
                for (int nt = 0; nt < 4; ++nt) {
                    int gcol = brow + nt * 16 + lane15;
                    float g = silu(acc[mt][nt][r] + bias[gcol]);
                    float p = g * bf2f(qv[r][nt]) * bf2f(kv[r][nt]);
                    p += __shfl_xor(p, 1);
                    p += __shfl_xor(p, 2);
                    p += __shfl_xor(p, 4);
                    p += __shfl_xor(p, 8);
                    if (lane15 == 0)
                        ((float*)out)[(size_t)(row0 + lr) * NHD + (brow >> 4) + nt] = p;
                }
            }
        }
    } else {
        #pragma unroll
        for (int mt = 0; mt < 4; ++mt)
            #pragma unroll
            for (int r = 0; r < 4; ++r) {
                int grow = row0 + arow + mt * 16 + quad * 4 + r;
                u16* orow = (u16*)out + (size_t)grow * Ncols;
                #pragma unroll
                for (int nt = 0; nt < 4; ++nt) {
                    int gcol = col0 + brow + nt * 16 + lane15;
                    float v = acc[mt][nt][r];
                    if (bias) v += bias[gcol];
                    if (act == 1 || (act == 2 && gcol >= 256)) v = silu(v);
                    orow[gcol] = f2bf(v);
                }
            }
    }
}

// ---------------- kernels wrapping mm_body ----------------
__global__ __launch_bounds__(256) void qkvs_kernel(
    const u16* h_bf, const u16* W, const float* b512, u16* qkvs)
{
    extern __shared__ char smem[];
    int t = blockIdx.x;
    mm_body<0, false>(smem, h_bf, nullptr, 128, 0, W, b512, qkvs, 512, 128, 2,
                      nullptr, nullptr, nullptr, nullptr, nullptr, t & 3, t >> 2);
}

__global__ __launch_bounds__(256) void mega_kernel(
    const u16* qkvs, const u16* Wv2T, const float* bv2, u16* hv_bf,
    const u16* Ws2T, const float* bs2, u16* hs_bf,
    const u16* t_bf, const u16* WreT, const float* bre, float* alpha,
    const int* edge)
{
    extern __shared__ char smem[];
    int t = blockIdx.x;
    if (t < 315) {
        mm_body<0, false>(smem, qkvs + 256, nullptr, 512, 0, Wv2T, bv2, hv_bf, 640, 128, 0,
                          nullptr, nullptr, nullptr, nullptr, nullptr, t % 5, t / 5);
    } else if (t < 630) {
        t -= 315;
        mm_body<0, false>(smem, qkvs + 384, nullptr, 512, 0, Ws2T, bs2, hs_bf, 640, 128, 0,
                          nullptr, nullptr, nullptr, nullptr, nullptr, t % 5, t / 5);
    } else {
        mm_body<4, false>(smem, t_bf, nullptr, 128, 0, WreT, bre, alpha, 128, 128, 0,
                          edge, nullptr, qkvs, nullptr, nullptr, 0, t - 630);
    }
}

__global__ __launch_bounds__(256) void coeff_kernel(
    const u16* t_bf, const u16* WrsT, const float* brs, u16* coeff,
    const int* edge, const float* attn, const u16* hv, const u16* hs, const float* cvals)
{
    extern __shared__ char smem[];
    mm_body<2, false>(smem, t_bf, nullptr, 128, 0, WrsT, brs, coeff, 640, 128, 0,
                      edge, attn, hv, hs, cvals, blockIdx.x, blockIdx.y);
}

__global__ __launch_bounds__(256) void qk_kernel(
    const float* X1_out, const u16* WA1T, u16* Q1K1,
    const float* X2_out, const u16* WA2T, u16* Q2K2)
{
    extern __shared__ char smem[];
    int t = blockIdx.x;
    if (t < 188) {
        mm_body<0, true>(smem, nullptr, X1_out, 128, 24000, WA1T, nullptr, Q1K1, 128, 128, 0,
                         nullptr, nullptr, nullptr, nullptr, nullptr, 0, t);
    } else {
        mm_body<0, true>(smem, nullptr, X2_out, 128, 40000, WA2T, nullptr, Q2K2, 128, 128, 0,
                         nullptr, nullptr, nullptr, nullptr, nullptr, 0, t - 188);
    }
}

// ---------------- CSR build ----------------
__global__ void count_kernel(const int* __restrict__ edge, int* __restrict__ cnt, int E_) {
    int e = blockIdx.x * 256 + threadIdx.x;
    if (e < E_) atomicAdd(&cnt[edge[2 * e]], 1);
}
__global__ __launch_bounds__(1024) void scan_kernel(const int* __restrict__ cnt, int* __restrict__ offs, int n) {
    __shared__ int s[1024];
    int t = threadIdx.x;
    int base = t * 8;
    int loc[8];
    int sum = 0;
    #pragma unroll
    for (int q = 0; q < 8; ++q) {
        int idx = base + q;
        int v = (idx < n) ? cnt[idx] : 0;
        loc[q] = v; sum += v;
    }
    s[t] = sum;
    __syncthreads();
    for (int off = 1; off < 1024; off <<= 1) {
        int v = (t >= off) ? s[t - off] : 0;
        __syncthreads();
        s[t] += v;
        __syncthreads();
    }
    int run = s[t] - sum;
    #pragma unroll
    for (int q = 0; q < 8; ++q) {
        int idx = base + q;
        if (idx < n) offs[idx] = run;
        run += loc[q];
    }
    if (t == 1023) offs[n] = s[1023];
}
__global__ void fill_kernel(const int* __restrict__ edge, const int* __restrict__ offs,
                            int* __restrict__ cursor, int* __restrict__ eids, int E_) {
    int e = blockIdx.x * 256 + threadIdx.x;
    if (e >= E_) return;
    int i = edge[2 * e];
    int pos = atomicAdd(&cursor[i], 1);
    eids[offs[i] + pos] = e;
}

// ---------------- per-node softmax ----------------
__global__ __launch_bounds__(64) void softmax_kernel(
    const float* __restrict__ alpha, const int* __restrict__ offs, const int* __restrict__ eids,
    float* __restrict__ attn)
{
    int node = blockIdx.x;
    int t = threadIdx.x;
    int g = t >> 3, hh = t & 7;
    int beg = offs[node], end = offs[node + 1];
    int deg = end - beg;
    __shared__ float sm[8][8];
    __shared__ float ss[8][8];
    float m = -1e9f;
    for (int p = beg + g; p < end; p += 8) {
        int e = eids[p];
        m = fmaxf(m, alpha[e * NHD + hh]);
    }
    sm[g][hh] = m;
    __syncthreads();
    if (g == 0) {
        float mm = sm[0][hh];
        #pragma unroll
        for (int q = 1; q < 8; ++q) mm = fmaxf(mm, sm[q][hh]);
        sm[0][hh] = mm;
    }
    __syncthreads();
    float mx = sm[0][hh];
    float ssum = 0.f;
    for (int p = beg + g; p < end; p += 8) {
        int e = eids[p];
        ssum += __expf(alpha[e * NHD + hh] - mx);
    }
    ss[g][hh] = ssum;
    __syncthreads();
    if (g == 0) {
        float tot = 0.f;
        #pragma unroll
        for (int q = 0; q < 8; ++q) tot += ss[q][hh];
        ss[0][hh] = fmaxf(tot, 1e-12f);
    }
    __syncthreads();
    float den = ss[0][hh];
    float scale = sqrtf((float)deg) * 0.08838834764831845f;
    for (int p = beg + g; p < end; p += 8) {
        int e = eids[p];
        attn[e * NHD + hh] = __expf(alpha[e * NHD + hh] - mx) / den * scale;
    }
}

// ---------------- per-node scatter accumulation (2-way edge parallel) ----------------
__global__ __launch_bounds__(256) void scatter_kernel(
    const u16* __restrict__ coeff, const int* __restrict__ edge,
    const float* __restrict__ r1, const float* __restrict__ r2,
    const float* __restrict__ h, const float* __restrict__ X1, const float* __restrict__ X2,
    const u16* __restrict__ X1bf, const u16* __restrict__ X2bf,
    const int* __restrict__ offs, const int* __restrict__ eids,
    float* __restrict__ h_out, float* __restrict__ X1_out, float* __restrict__ X2_out)
{
    int n = blockIdx.x;
    int d = threadIdx.x & 127;
    int g = threadIdx.x >> 7;
    int beg = offs[n], end = offs[n + 1];
    float hacc = 0.f;
    float x1a[3] = {0.f, 0.f, 0.f};
    float x2a[5] = {0.f, 0.f, 0.f, 0.f, 0.f};
    for (int p = beg + g; p < end; p += 2) {
        int e = eids[p];
        int j = edge[2 * e + 1];
        const u16* crow = coeff + (size_t)e * CDIM;
        const u16* x1r = X1bf + (size_t)j * 3 * DNE;
        const u16* x2r = X2bf + (size_t)j * 5 * DNE;
        float c0  = bf2f(crow[d]);
        float od1 = bf2f(crow[128 + d]);
        float od2 = bf2f(crow[256 + d]);
        float ot1 = bf2f(crow[384 + d]);
        float ot2 = bf2f(crow[512 + d]);
        hacc += c0;
        #pragma unroll
        for (int a = 0; a < 3; ++a)
            x1a[a] += r1[e * 3 + a] * od1 + bf2f(x1r[a * DNE + d]) * ot1;
        #pragma unroll
        for (int a = 0; a < 5; ++a)
            x2a[a] += r2[e * 5 + a] * od2 + bf2f(x2r[a * DNE + d]) * ot2;
    }
    __shared__ float red[1152];
    if (g == 1) {
        red[d] = hacc;
        #pragma unroll
        for (int a = 0; a < 3; ++a) red[128 + a * 128 + d] = x1a[a];
        #pragma unroll
        for (int a = 0; a < 5; ++a) red[512 + a * 128 + d] = x2a[a];
    }
    __syncthreads();
    if (g == 0) {
        hacc += red[d];
        h_out[(size_t)n * DNE + d] = h[(size_t)n * DNE + d] + hacc;
        #pragma unroll
        for (int a = 0; a < 3; ++a) {
            size_t idx = ((size_t)n * 3 + a) * DNE + d;
            X1_out[idx] = X1[idx] + x1a[a] + red[128 + a * 128 + d];
        }
        #pragma unroll
        for (int a = 0; a < 5; ++a) {
            size_t idx = ((size_t)n * 5 + a) * DNE + d;
            X2_out[idx] = X2[idx] + x2a[a] + red[512 + a * 128 + d];
        }
    }
}

// ---------------- w = sum_a rej(Q) . rej(K)  (rej(x,-r)==rej(x,r)) ----------------
__global__ __launch_bounds__(256) void w_kernel(
    const u16* __restrict__ QK1, const u16* __restrict__ QK2,
    const int* __restrict__ edge, const float* __restrict__ r1, const float* __restrict__ r2,
    u16* __restrict__ w, int E_)
{
    int e = blockIdx.x * 4 + (threadIdx.x >> 6);
    int d = threadIdx.x & 63;
    if (e >= E_) return;
    int i = edge[2 * e], j = edge[2 * e + 1];
    float q[8], k[8];
    #pragma unroll
    for (int a = 0; a < 3; ++a) {
        q[a] = bf2f(QK1[((size_t)i * 3 + a) * 128 + d]);
        k[a] = bf2f(QK1[((size_t)j * 3 + a) * 128 + 64 + d]);
    }
    #pragma unroll
    for (int a = 0; a < 5; ++a) {
        q[3 + a] = bf2f(QK2[((size_t)i * 5 + a) * 128 + d]);
        k[3 + a] = bf2f(QK2[((size_t)j * 5 + a) * 128 + 64 + d]);
    }
    float ra[3], rb[5];
    #pragma unroll
    for (int a = 0; a < 3; ++a) ra[a] = r1[e * 3 + a];
    #pragma unroll
    for (int a = 0; a < 5; ++a) rb[a] = r2[e * 5 + a];
    float dq1 = 0.f, dk1 = 0.f, dq2 = 0.f, dk2 = 0.f;
    #pragma unroll
    for (int a = 0; a < 3; ++a) { dq1 += q[a] * ra[a]; dk1 += k[a] * ra[a]; }
    #pragma unroll
    for (int a = 0; a < 5; ++a) { dq2 += q[3 + a] * rb[a]; dk2 += k[3 + a] * rb[a]; }
    float acc = 0.f;
    #pragma unroll
    for (int a = 0; a < 3; ++a) acc += (q[a] - dq1 * ra[a]) * (k[a] - dk1 * ra[a]);
    #pragma unroll
    for (int a = 0; a < 5; ++a) acc += (q[3 + a] - dq2 * rb[a]) * (k[3 + a] - dk2 * rb[a]);
    w[(size_t)e * 64 + d] = f2bf(acc);
}

// ---------------- chained MLP: wout = silu(w@W1+b1)@W2+b2 ----------------
__global__ __launch_bounds__(256) void wchain_kernel(
    const u16* __restrict__ wbuf, const u16* __restrict__ W1T, const u16* __restrict__ W2T,
    const float* __restrict__ b1, const float* __restrict__ b2, u16* __restrict__ wout)
{
    __shared__ u16 sw[128 * 72];
    __shared__ u16 sm[128 * 72];
    __shared__ u16 sW1[64 * 72];
    __shared__ u16 sW2[128 * 72];
    const int tid = threadIdx.x;
    const int wave = tid >> 6, lane = tid & 63;
    const int lane15 = lane & 15, quad = lane >> 4;
    const int row0 = blockIdx.x * 128;
    #pragma unroll
    for (int ci = 0; ci < 4; ++ci) {
        int cch = tid + ci * 256;
        int m = cch >> 3, ko = (cch & 7) * 8;
        *(u16x8*)(&sw[m * 72 + ko]) = *(const u16x8*)(wbuf + (size_t)(row0 + m) * 64 + ko);
    }
    #pragma unroll
    for (int ci = 0; ci < 2; ++ci) {
        int cch = tid + ci * 256;
        int n = cch >> 3, ko = (cch & 7) * 8;
        *(u16x8*)(&sW1[n * 72 + ko]) = *(const u16x8*)(W1T + (size_t)n * 64 + ko);
    }
    #pragma unroll
    for (int ci = 0; ci < 4; ++ci) {
        int cch = tid + ci * 256;
        int n = cch >> 3, ko = (cch & 7) * 8;
        *(u16x8*)(&sW2[n * 72 + ko]) = *(const u16x8*)(W2T + (size_t)n * 64 + ko);
    }
    __syncthreads();
    v4f a1[2][4] = {};
    #pragma unroll
    for (int kk = 0; kk < 2; ++kk) {
        int k0 = kk * 32;
        v8bf af[2], bfr[4];
        #pragma unroll
        for (int mt = 0; mt < 2; ++mt)
            af[mt] = __builtin_bit_cast(v8bf, *(const u16x8*)(&sw[(wave * 32 + mt * 16 + lane15) * 72 + k0 + quad * 8]));
        #pragma unroll
        for (int nt = 0; nt < 4; ++nt)
            bfr[nt] = __builtin_bit_cast(v8bf, *(const u16x8*)(&sW1[(nt * 16 + lane15) * 72 + k0 + quad * 8]));
        #pragma unroll
        for (int mt = 0; mt < 2; ++mt)
            #pragma unroll
            for (int nt = 0; nt < 4; ++nt)
                a1[mt][nt] = __builtin_amdgcn_mfma_f32_16x16x32_bf16(af[mt], bfr[nt], a1[mt][nt], 0, 0, 0);
    }
    #pragma unroll
    for (int mt = 0; mt < 2; ++mt)
        #pragma unroll
        for (int r = 0; r < 4; ++r) {
            int mrow = wave * 32 + mt * 16 + quad * 4 + r;
            #pragma unroll
            for (int nt = 0; nt < 4; ++nt) {
                int mcol = nt * 16 + lane15;
                sm[mrow * 72 + mcol] = f2bf(silu(a1[mt][nt][r] + b1[mcol]));
            }
        }
    __syncthreads();
    const int wm = wave >> 1, wn = wave & 1;
    const int arow = wm * 64, brow = wn * 64;
    v4f a2[4][4] = {};
    #pragma unroll
    for (int kk = 0; kk < 2; ++kk) {
        int k0 = kk * 32;
        v8bf af[4], bfr[4];
        #pragma unroll
        for (int mt = 0; mt < 4; ++mt)
            af[mt] = __builtin_bit_cast(v8bf, *(const u16x8*)(&sm[(arow + mt * 16 + lane15) * 72 + k0 + quad * 8]));
        #pragma unroll
        for (int nt = 0; nt < 4; ++nt)
            bfr[nt] = __builtin_bit_cast(v8bf, *(const u16x8*)(&sW2[(brow + nt * 16 + lane15) * 72 + k0 + quad * 8]));
        #pragma unroll
        for (int mt = 0; mt < 4; ++mt)
            #pragma unroll
            for (int nt = 0; nt < 4; ++nt)
                a2[mt][nt] = __builtin_amdgcn_mfma_f32_16x16x32_bf16(af[mt], bfr[nt], a2[mt][nt], 0, 0, 0);
    }
    #pragma unroll
    for (int mt = 0; mt < 4; ++mt)
        #pragma unroll
        for (int r = 0; r < 4; ++r) {
            int grow = row0 + arow + mt * 16 + quad * 4 + r;
            #pragma unroll
            for (int nt = 0; nt < 4; ++nt) {
                int gcol = brow + nt * 16 + lane15;
                wout[(size_t)grow * 128 + gcol] = f2bf(a2[mt][nt][r] + b2[gcol]);
            }
        }
}

// ---------------- chained MLP: t_out = t + wout * (silu(t@Wt1+b1)@Wt2+b2) ----------------
__global__ __launch_bounds__(256) void tchain_kernel(
    const u16* __restrict__ tbf, const u16* __restrict__ W1T, const u16* __restrict__ W2T,
    const float* __restrict__ b1, const float* __restrict__ b2,
    const float* __restrict__ tin, const u16* __restrict__ wout,
    float* __restrict__ t_out)
{
    constexpr int LDA = 136;
    __shared__ u16 sA[128 * LDA];
    __shared__ u16 sW[128 * 72];
    const int tid = threadIdx.x;
    const int wave = tid >> 6, lane = tid & 63;
    const int lane15 = lane & 15, quad = lane >> 4;
    const int wm = wave >> 1, wn = wave & 1;
    const int arow = wm * 64, brow = wn * 64;
    const int row0 = blockIdx.x * 128;
    #pragma unroll
    for (int ci = 0; ci < 8; ++ci) {
        int cch = tid + ci * 256;
        int m = cch >> 4, ko = (cch & 15) * 8;
        *(u16x8*)(&sA[m * LDA + ko]) = *(const u16x8*)(tbf + (size_t)(row0 + m) * 128 + ko);
    }
    v4f acc[4][4] = {};
    #pragma unroll
    for (int kh = 0; kh < 2; ++kh) {
        __syncthreads();
        #pragma unroll
        for (int ci = 0; ci < 4; ++ci) {
            int cch = tid + ci * 256;
            int n = cch >> 3, ko = (cch & 7) * 8;
            *(u16x8*)(&sW[n * 72 + ko]) = *(const u16x8*)(W1T + (size_t)n * 128 + kh * 64 + ko);
        }
        __syncthreads();
        #pragma unroll
        for (int kk = 0; kk < 2; ++kk) {
            int k0 = kh * 64 + kk * 32;
            v8bf af[4], bfr[4];
            #pragma unroll
            for (int mt = 0; mt < 4; ++mt)
                af[mt] = __builtin_bit_cast(v8bf, *(const u16x8*)(&sA[(arow + mt * 16 + lane15) * LDA + k0 + quad * 8]));
            #pragma unroll
            for (int nt = 0; nt < 4; ++nt)
                bfr[nt] = __builtin_bit_cast(v8bf, *(const u16x8*)(&sW[(brow + nt * 16 + lane15) * 72 + kk * 32 + quad * 8]));
            #pragma unroll
            for (int mt = 0; mt < 4; ++mt)
                #pragma unroll
                for (int nt = 0; nt < 4; ++nt)
                    acc[mt][nt] = __builtin_amdgcn_mfma_f32_16x16x32_bf16(af[mt], bfr[nt], acc[mt][nt], 0, 0, 0);
        }
    }
    __syncthreads();
    #pragma unroll
    for (int mt = 0; mt < 4; ++mt)
        #pragma unroll
        for (int r = 0; r < 4; ++r) {
            int mrow = arow + mt * 16 + quad * 4 + r;
            #pragma unroll
            for (int nt = 0; nt < 4; ++nt) {
                int mcol = brow + nt * 16 + lane15;
                sA[mrow * LDA + mcol] = f2bf(silu(acc[mt][nt][r] + b1[mcol]));
            }
        }
    v4f acc2[4][4] = {};
    #pragma unroll
    for (int kh = 0; kh < 2; ++kh) {
        __syncthreads();
        #pragma unroll
        for (int ci = 0; ci < 4; ++ci) {
            int cch = tid + ci * 256;
            int n = cch >> 3, ko = (cch & 7) * 8;
            *(u16x8*)(&sW[n * 72 + ko]) = *(const u16x8*)(W2T + (size_t)n * 128 + kh * 64 + ko);
        }
        __syncthreads();
        #pragma unroll
        for (int kk = 0; kk < 2; ++kk) {
            int k0 = kh * 64 + kk * 32;
            v8bf af[4], bfr[4];
            #pragma unroll
            for (int mt = 0; mt < 4; ++mt)
                af[mt] = __builtin_bit_cast(v8bf, *(const u16x8*)(&sA[(arow + mt * 16 + lane15) * LDA + k0 + quad * 8]));
            #pragma unroll
            for (int nt = 0; nt < 4; ++nt)
                bfr[nt] = __builtin_bit_cast(v8bf, *(const u16x8*)(&sW[(brow + nt * 16 + lane15) * 72 + kk * 32 + quad * 8]));
            #pragma unroll
            for (int mt = 0; mt < 4; ++mt)
                #pragma unroll
                for (int nt = 0; nt < 4; ++nt)
                    acc2[mt][nt] = __builtin_amdgcn_mfma_f32_16x16x32_bf16(af[mt], bfr[nt], acc2[mt][nt], 0, 0, 0);
        }
    }
    #pragma unroll
    for (int mt = 0; mt < 4; ++mt)
        #pragma unroll
        for (int r = 0; r < 4; ++r) {
            int grow = row0 + arow + mt * 16 + quad * 4 + r;
            size_t base = (size_t)grow * 128;
            #pragma unroll
            for (int nt = 0; nt < 4; ++nt) {
                int gcol = brow + nt * 16 + lane15;
                float v = acc2[mt][nt][r] + b2[gcol];
                t_out[base + gcol] = tin[base + gcol] + bf2f(wout[base + gcol]) * v;
            }
        }
}

extern "C" void kernel_launch(void* const* d_in, const int* in_sizes, int n_in,
                              void* d_out, int out_size, void* d_ws, size_t ws_size,
                              hipStream_t stream)
{
    const float* h    = (const float*)d_in[0];
    const float* t    = (const float*)d_in[1];
    const float* X1   = (const float*)d_in[2];
    const float* X2   = (const float*)d_in[3];
    const float* r1   = (const float*)d_in[4];
    const float* r2   = (const float*)d_in[5];
    const float* c    = (const float*)d_in[6];
    const int*   edge = (const int*)d_in[7];
    const float* Wq   = (const float*)d_in[8];  const float* bq  = (const float*)d_in[9];
    const float* Wk   = (const float*)d_in[10]; const float* bk  = (const float*)d_in[11];
    const float* Wre  = (const float*)d_in[12]; const float* bre = (const float*)d_in[13];
    const float* Wv1  = (const float*)d_in[14]; const float* bv1 = (const float*)d_in[15];
    const float* Wv2  = (const float*)d_in[16]; const float* bv2 = (const float*)d_in[17];
    const float* Wrs  = (const float*)d_in[18]; const float* brs = (const float*)d_in[19];
    const float* Ws1  = (const float*)d_in[20]; const float* bs1 = (const float*)d_in[21];
    const float* Ws2  = (const float*)d_in[22]; const float* bs2 = (const float*)d_in[23];
    const float* Wvq  = (const float*)d_in[24];
    const float* Wvk1 = (const float*)d_in[25];
    const float* Wvk2 = (const float*)d_in[26];
    const float* Ww1  = (const float*)d_in[27]; const float* bw1 = (const float*)d_in[28];
    const float* Ww2  = (const float*)d_in[29]; const float* bw2 = (const float*)d_in[30];
    const float* Wt1  = (const float*)d_in[31]; const float* bt1 = (const float*)d_in[32];
    const float* Wt2  = (const float*)d_in[33]; const float* bt2 = (const float*)d_in[34];

    char* ws = (char*)d_ws;
    float* h_out  = (float*)d_out;
    float* t_out  = h_out + (size_t)NN * DNE;
    float* X1_out = t_out + (size_t)NE * 128;
    float* X2_out = X1_out + (size_t)NN * 3 * DNE;

    u16* t_bf   = (u16*)(ws + O_TBF);
    u16* X1bf   = (u16*)(ws + O_X1BF);
    u16* X2bf   = (u16*)(ws + O_X2BF);
    u16* ware   = (u16*)(ws + O_WARE);
    int* cnt    = (int*)(ws + O_CNT);
    int* cursor = (int*)(ws + O_CURS);
    int* offs   = (int*)(ws + O_OFFS);
    int* eids   = (int*)(ws + O_EIDS);
    u16* hv_bf  = (u16*)(ws + O_HV);
    u16* hs_bf  = (u16*)(ws + O_HS);
    float* attn = (float*)(ws + O_ATTN);
    float* bias512 = (float*)(ws + O_B512);
    u16* qkvs   = (u16*)(ws + O_QKVS);
    float* alpha= (float*)(ws + O_ALPHA);
    u16* h_bf   = (u16*)(ws + O_HBF);
    u16* coeff  = (u16*)(ws + O_COEFF);
    u16* Q1K1   = (u16*)(ws + O_Q1K1);
    u16* Q2K2   = (u16*)(ws + O_Q2K2);
    u16* wbuf   = (u16*)(ws + O_WBUF);
    u16* wout   = (u16*)(ws + O_WOUT);

    u16* WqkvsT = ware + 0;
    u16* WreT = ware + 65536;
    u16* Wt1T = ware + 81920;
    u16* Wt2T = ware + 98304;
    u16* Wv2T = ware + 114688;
    u16* WrsT = ware + 196608;
    u16* Ws2T = ware + 278528;
    u16* Ww1T = ware + 360448;
    u16* Ww2T = ware + 364544;
    u16* WA1T = ware + 372736;
    u16* WA2T = ware + 389120;

    // ---- weights + bias pack + CSR zeroing ----
    WTArgs wt;
    wt.w[0] = Wq;  wt.w[1] = Wk;  wt.w[2] = Wv1; wt.w[3] = Ws1; wt.w[4] = Wre;
    wt.w[5] = Wt1; wt.w[6] = Wt2; wt.w[7] = Wv2; wt.w[8] = Wrs; wt.w[9] = Ws2;
    wt.w[10] = Ww1; wt.w[11] = Ww2; wt.w[12] = Wvq; wt.w[13] = Wvk1; wt.w[14] = Wvq; wt.w[15] = Wvk2;
    wt.b[0] = bq; wt.b[1] = bk; wt.b[2] = bv1; wt.b[3] = bs1;
    wtrans_all<<<dim3(320, 16), 256, 0, stream>>>(wt, ware, bias512, cnt);

    // ---- activations -> bf16 ----
    ConvArgs ca;
    ca.in[0] = h;  ca.out[0] = h_bf;
    ca.in[1] = t;  ca.out[1] = t_bf;
    ca.in[2] = X1; ca.out[2] = X1bf;
    ca.in[3] = X2; ca.out[3] = X2bf;
    conv_all<<<dim3(8000, 4), 256, 0, stream>>>(ca);

    // ---- CSR ----
    count_kernel<<<250, 256, 0, stream>>>(edge, cnt, NE);
    scan_kernel<<<1, 1024, 0, stream>>>(cnt, offs, NN);
    fill_kernel<<<250, 256, 0, stream>>>(edge, offs, cursor, eids, NE);

    // ---- node projections ----
    qkvs_kernel<<<252, 256, 20480, stream>>>(h_bf, WqkvsT, bias512, qkvs);

    // ---- hv + hs + alpha merged ----
    mega_kernel<<<1130, 256, 21504, stream>>>(qkvs, Wv2T, bv2, hv_bf, Ws2T, bs2, hs_bf,
                                              t_bf, WreT, bre, alpha, edge);
    softmax_kernel<<<NN, 64, 0, stream>>>(alpha, offs, eids, attn);

    // ---- coeff GEMM (fused epilogue, pipelined gathers) ----
    coeff_kernel<<<dim3(5, 500), 256, 25600, stream>>>(t_bf, WrsT, brs, coeff,
                                                       edge, attn, hv_bf, hs_bf, c);

    // ---- scatter ----
    scatter_kernel<<<NN, 256, 0, stream>>>(coeff, edge, r1, r2, h, X1, X2, X1bf, X2bf,
                                           offs, eids, h_out, X1_out, X2_out);

    // ---- Q|K packed projections (read X_out fp32 directly) ----
    qk_kernel<<<501, 256, 20480, stream>>>(X1_out, WA1T, Q1K1, X2_out, WA2T, Q2K2);

    // ---- w ----
    w_kernel<<<NE / 4, 256, 0, stream>>>(Q1K1, Q2K2, edge, r1, r2, wbuf, NE);

    // ---- chained MLPs ----
    wchain_kernel<<<500, 256, 0, stream>>>(wbuf, Ww1T, Ww2T, bw1, bw2, wout);
    tchain_kernel<<<500, 256, 0, stream>>>(t_bf, Wt1T, Wt2T, bt1, bt2, t, wout, t_out);
}